// Round 8
// baseline (104.573 us; speedup 1.0000x reference)
//
#include <hip/hip_runtime.h>
#include <hip/hip_fp16.h>
#include <math.h>

#define OBJ_D 320
#define LANG_D 256
#define GEO_D 6
#define HID 256
#define NN 512
#define BATCH 2
#define BN (BATCH * NN)

// gelu(a) ~= 0.5a + GK0*a^2 + GK1*a^4,  GK1 = -GK0/6.
// Factorized: score = Ci + Dj + 2*GK0*sum_h (W2*x_i)*v_j (quartic cross ~1e-8, dropped)
#define GK0 0.3989422804014327f
#define GK1 (-0.066490380066905448f)
#define SCA (512.0f * GK0)
#define INV_SCA (1.0f / 256.0f)

typedef _Float16 v8h __attribute__((ext_vector_type(8)));
typedef float f32x4 __attribute__((ext_vector_type(4)));

__device__ __forceinline__ float wave_allreduce_sum(float v) {
#pragma unroll
    for (int o = 32; o > 0; o >>= 1) v += __shfl_xor(v, o, 64);
    return v;
}
__device__ __forceinline__ float wave_allreduce_max(float v) {
#pragma unroll
    for (int o = 32; o > 0; o >>= 1) v = fmaxf(v, __shfl_xor(v, o, 64));
    return v;
}

// k_pre v8 = round-4 verbatim (best measured; ILP-4 / 1 wave/SIMD is the
// optimum of the fixed-work ILP/TLP trade — v7's 2-wave split lost 2.1 us).
// 256 compute blocks = (row-group g: 16 rows, H-quarter q: 64 cols); one
// barrier; matmul on UNNORMALIZED esT post-scaled by rnv (linear).
// blocks 256..257 = lang norm + hl matvec (b1 folded).
__global__ __launch_bounds__(256) void k_pre(const float* __restrict__ emb,
                                             const float* __restrict__ geom,
                                             const float* __restrict__ utter,
                                             const float* __restrict__ W1,
                                             const float* __restrict__ b1,
                                             const float* __restrict__ W2,
                                             __half2* __restrict__ embT2,
                                             float* __restrict__ hi_p,
                                             _Float16* __restrict__ Bj_h,
                                             float* __restrict__ hl,
                                             float* __restrict__ DjP) {
    int tid = threadIdx.x;
    int wid = tid >> 6, lane = tid & 63;

    __shared__ alignas(16) float esT[OBJ_D * 20];   // [d][16 rows + pad4]
    __shared__ float gs[16][GEO_D];
    __shared__ float lang_s[LANG_D];
    __shared__ float red[8];

    if (blockIdx.x >= 256) {
        int lb = blockIdx.x - 256;
        float v = utter[lb * LANG_D + tid];
        float ss = wave_allreduce_sum(v * v);
        if (lane == 0) red[wid] = ss;
        __syncthreads();
        if (tid == 0) red[0] = 1.0f / fmaxf(sqrtf(red[0] + red[1] + red[2] + red[3]), 1e-12f);
        __syncthreads();
        lang_s[tid] = v * red[0];
        __syncthreads();
        const float* Wl = W1 + (size_t)(2 * OBJ_D + GEO_D) * HID + tid;
        float acc = b1[tid];
#pragma unroll 8
        for (int l2 = 0; l2 < LANG_D; l2++) acc = fmaf(lang_s[l2], Wl[(size_t)l2 * HID], acc);
        hl[lb * HID + tid] = acc;
        return;
    }

    int q = blockIdx.x & 3;
    int g = blockIdx.x >> 2;
    int b = g & 1;
    int n0 = (g >> 1) * 16;
    int h = q * 64 + lane;     // this thread's H column
    int rg = wid;              // wave owns rows 4*rg .. 4*rg+3

    // stage emb 16 rows x 320 -> esT[d][r] (transposed, +4 pad)
    const float* esrc = emb + (size_t)(b * NN + n0) * OBJ_D;
#pragma unroll
    for (int it = 0; it < 20; it++) {
        int idx = it * 256 + tid;              // 0..5119
        int r = idx / OBJ_D, d = idx - r * OBJ_D;
        esT[d * 20 + r] = esrc[idx];
    }
    if (tid < 16 * GEO_D) gs[tid / GEO_D][tid % GEO_D] = geom[(size_t)(b * NN + n0) * GEO_D + tid];

    // W prefetch (first 16 dims) issues while esT settles; drained at the barrier
    const float* WiC = W1 + h;
    const float* WjC = W1 + (size_t)OBJ_D * HID + h;
    float wi[16], wj[16], win[16], wjn[16];
#pragma unroll
    for (int k = 0; k < 16; k++) {
        wi[k] = WiC[(size_t)k * HID];
        wj[k] = WjC[(size_t)k * HID];
    }
    __syncthreads();

    // per-wave norms for its 4 rows (wave-local; no broadcast barrier)
    float rnv[4];
    {
        float sq0 = 0.0f, sq1 = 0.0f, sq2 = 0.0f, sq3 = 0.0f;
#pragma unroll
        for (int it = 0; it < 5; it++) {
            float4 e4 = *(const float4*)&esT[(lane + 64 * it) * 20 + 4 * rg];
            sq0 = fmaf(e4.x, e4.x, sq0); sq1 = fmaf(e4.y, e4.y, sq1);
            sq2 = fmaf(e4.z, e4.z, sq2); sq3 = fmaf(e4.w, e4.w, sq3);
        }
        rnv[0] = 1.0f / fmaxf(sqrtf(wave_allreduce_sum(sq0)), 1e-12f);
        rnv[1] = 1.0f / fmaxf(sqrtf(wave_allreduce_sum(sq1)), 1e-12f);
        rnv[2] = 1.0f / fmaxf(sqrtf(wave_allreduce_sum(sq2)), 1e-12f);
        rnv[3] = 1.0f / fmaxf(sqrtf(wave_allreduce_sum(sq3)), 1e-12f);
    }

    // embT2[b][d][jpair] from q==0 blocks only; wave w writes its own 2 pairs
    if (q == 0) {
#pragma unroll
        for (int it = 0; it < 10; it++) {
            int idx = it * 64 + lane;          // 0..639
            int d = idx >> 1, pp = idx & 1;
            int rp = 2 * rg + pp;
            float ra = pp ? rnv[2] : rnv[0];
            float rc = pp ? rnv[3] : rnv[1];
            float a = esT[d * 20 + 2 * rp] * ra;
            float c = esT[d * 20 + 2 * rp + 1] * rc;
            embT2[((size_t)(b * OBJ_D + d)) * 256 + (n0 >> 1) + rp] = __floats2half2_rn(a, c);
        }
    }

    // dual matmul on UNNORMALIZED esT (rows 4rg..4rg+3, this thread's h col)
    float ai[4] = {0, 0, 0, 0}, aj[4] = {0, 0, 0, 0};
    for (int d0 = 0; d0 < OBJ_D; d0 += 16) {
        if (d0 + 16 < OBJ_D) {
#pragma unroll
            for (int k = 0; k < 16; k++) {
                win[k] = WiC[(size_t)(d0 + 16 + k) * HID];
                wjn[k] = WjC[(size_t)(d0 + 16 + k) * HID];
            }
        }
#pragma unroll
        for (int k = 0; k < 16; k++) {
            float4 e4 = *(const float4*)&esT[(d0 + k) * 20 + 4 * rg];   // wave-uniform broadcast
            ai[0] = fmaf(e4.x, wi[k], ai[0]); aj[0] = fmaf(e4.x, wj[k], aj[0]);
            ai[1] = fmaf(e4.y, wi[k], ai[1]); aj[1] = fmaf(e4.y, wj[k], aj[1]);
            ai[2] = fmaf(e4.z, wi[k], ai[2]); aj[2] = fmaf(e4.z, wj[k], aj[2]);
            ai[3] = fmaf(e4.w, wi[k], ai[3]); aj[3] = fmaf(e4.w, wj[k], aj[3]);
        }
#pragma unroll
        for (int k = 0; k < 16; k++) { wi[k] = win[k]; wj[k] = wjn[k]; }
    }

    float gw[GEO_D];
#pragma unroll
    for (int gg = 0; gg < GEO_D; gg++) gw[gg] = W1[(size_t)(2 * OBJ_D + gg) * HID + h];
    float w2v = W2[h];
#pragma unroll
    for (int r = 0; r < 4; r++) {
        int row = 4 * rg + r;
        float gp = 0.0f;
#pragma unroll
        for (int gg = 0; gg < GEO_D; gg++) gp = fmaf(gs[row][gg], gw[gg], gp);
        float yi = ai[r] * rnv[r] - gp;
        float vjv = aj[r] * rnv[r] + gp;
        hi_p[(size_t)(b * NN + n0 + row) * HID + h] = yi;
        Bj_h[((size_t)(b * NN + n0 + row)) * HID + h] = (_Float16)vjv;
        float v2 = vjv * vjv;
        float sj = fmaf(v2, fmaf(GK1, v2, GK0), 0.5f * vjv);
        float ds = wave_allreduce_sum(w2v * sj);   // partial over this block's 64 h
        if (lane == 0) DjP[q * BN + b * NN + n0 + row] = ds;
    }
}

__device__ __forceinline__ void load_tile8(v8h* dst, const _Float16* bp) {
#pragma unroll
    for (int t = 0; t < 8; t++) dst[t] = *(const v8h*)(bp + t * 32);
}

__device__ __forceinline__ void score_tile4(const v8h* afr, const v8h* bt,
                                            float (*S)[516], int srow0, int col, float dj) {
    f32x4 cA = {0.0f, 0.0f, 0.0f, 0.0f}, cB = {0.0f, 0.0f, 0.0f, 0.0f};
#pragma unroll
    for (int t = 0; t < 4; t++) {
        cA = __builtin_amdgcn_mfma_f32_16x16x32_f16(afr[2 * t], bt[2 * t], cA, 0, 0, 0);
        cB = __builtin_amdgcn_mfma_f32_16x16x32_f16(afr[2 * t + 1], bt[2 * t + 1], cB, 0, 0, 0);
    }
    f32x4 cc = cA + cB;
    if (srow0 == 0) {
#pragma unroll
        for (int r = 0; r < 4; r++) S[r][col] = cc[r] * INV_SCA + dj;
    }
}

// k_main v8: 256 blocks = (b, 4 i-rows) -> FULL machine (was 128 blocks, half
// the CUs idle). Per-block serial latency chain /4; MFMA count per block
// unchanged (M=16 rows 4..15 garbage-inert by row separation — As/El declared
// [16] so fragment reads stay in-bounds; S-writes/stores gated srow0==0,
// pattern verified in round 2's stage B).
__global__ __launch_bounds__(512, 2) void k_main(const float* __restrict__ hi_p,
                                                 const _Float16* __restrict__ Bj_h,
                                                 const __half2* __restrict__ embT2,
                                                 const float* __restrict__ hl,
                                                 const float* __restrict__ W2,
                                                 const float* __restrict__ b2p,
                                                 const float* __restrict__ DjP,
                                                 float* __restrict__ out) {
    int b = blockIdx.x & 1;
    int i0 = (blockIdx.x >> 1) * 4;
    int tid = threadIdx.x;
    int lane = tid & 63, w = tid >> 6;
    int ar = lane & 15, ag = (lane >> 4) * 8;
    int srow0 = (lane >> 4) * 4;

    __shared__ alignas(16) _Float16 As[16][264];    // rows 0..3 valid
    __shared__ float S[4][516];
    __shared__ alignas(16) _Float16 El[16][520];    // rows 0..3 valid
    __shared__ float red8[8], sumL[4], dotL[4];

    const _Float16* Bb = Bj_h + (size_t)b * NN * HID;
    const float* Djb = DjP + b * NN;
    int jt0 = w * 4;

    // pre-barrier prefetch: q=0 B-tile + all Dj partials (independent of As)
    v8h bA[8], bB[8];
    float dj[4];
    load_tile8(bA, Bb + (size_t)(jt0 * 16 + ar) * HID + ag);
#pragma unroll
    for (int qq = 0; qq < 4; qq++) {
        int jj = (jt0 + qq) * 16 + ar;
        dj[qq] = (Djb[jj] + Djb[jj + BN]) + (Djb[jj + 2 * BN] + Djb[jj + 3 * BN]);
    }

    // ---- phase 0: As = SCA*W2*(hi+hl) f16 (rows 0..3); Ci exact fp32 ----
    {
        int row = tid >> 7;              // 0..3 (128 threads = 2 waves per row)
        int hq = (tid & 127) * 2;        // 0..254
        float2 h2 = *(const float2*)&hi_p[((size_t)(b * NN + i0 + row)) * HID + hq];
        float2 l2 = *(const float2*)&hl[b * HID + hq];
        float2 w2 = *(const float2*)&W2[hq];
        float x0 = h2.x + l2.x, x1 = h2.y + l2.y;
        As[row][hq]     = (_Float16)(x0 * w2.x * SCA);
        As[row][hq + 1] = (_Float16)(x1 * w2.y * SCA);
        float x0s = x0 * x0, x1s = x1 * x1;
        float ci = fmaf(w2.x, fmaf(x0s, fmaf(GK1, x0s, GK0), 0.5f * x0),
                        w2.y * fmaf(x1s, fmaf(GK1, x1s, GK0), 0.5f * x1));
        ci = wave_allreduce_sum(ci);
        if (lane == 0) red8[w] = ci;     // wave w covers row w>>1, half w&1
    }
    __syncthreads();

    // ---- phase 1: score cross GEMM, 2-deep pipeline (valid rows 0..3) ----
    {
        v8h afr[8];
#pragma unroll
        for (int t = 0; t < 8; t++) afr[t] = *(const v8h*)&As[ar][t * 32 + ag];
        load_tile8(bB, Bb + (size_t)((jt0 + 1) * 16 + ar) * HID + ag);
        score_tile4(afr, bA, S, srow0, jt0 * 16 + ar, dj[0]);
        load_tile8(bA, Bb + (size_t)((jt0 + 2) * 16 + ar) * HID + ag);
        score_tile4(afr, bB, S, srow0, (jt0 + 1) * 16 + ar, dj[1]);
        load_tile8(bB, Bb + (size_t)((jt0 + 3) * 16 + ar) * HID + ag);
        score_tile4(afr, bA, S, srow0, (jt0 + 2) * 16 + ar, dj[2]);
        score_tile4(afr, bB, S, srow0, (jt0 + 3) * 16 + ar, dj[3]);
    }
    __syncthreads();

    // phase-3 first-tile prefetch: flies under the softmax VALU work
    const __half2* Eb = embT2 + (size_t)b * OBJ_D * 256;
    v8h eT[16];
    {
        const __half2* bp = Eb + (size_t)(w * 16 + ar) * 256 + (ag >> 1);
#pragma unroll
        for (int t = 0; t < 16; t++) eT[t] = *(const v8h*)(bp + t * 16);
    }

    // ---- phase 2: softmax — waves 0..3, one wave per row, 8 j per lane ----
    if (tid < 256) {
        int row = w;                     // 0..3
        float sv[8];
#pragma unroll
        for (int jj = 0; jj < 8; jj++) sv[jj] = S[row][lane + 64 * jj];
        float m = sv[0];
#pragma unroll
        for (int jj = 1; jj < 8; jj++) m = fmaxf(m, sv[jj]);
        m = wave_allreduce_max(m);
        float se = 0.0f, sd = 0.0f;
#pragma unroll
        for (int jj = 0; jj < 8; jj++) {
            float e = __expf(sv[jj] - m);
            se += e;
            sd = fmaf(e, sv[jj], sd);
            El[row][lane + 64 * jj] = (_Float16)e;
        }
        se = wave_allreduce_sum(se);
        sd = wave_allreduce_sum(sd);
        if (lane == 0) { sumL[row] = se; dotL[row] = sd; }
    }
    __syncthreads();

    if (tid < 4)
        out[b * NN + i0 + tid] = (red8[2 * tid] + red8[2 * tid + 1]) + b2p[0]
                                 + dotL[tid] / sumL[tid];

    // ---- phase 3: context GEMM (valid rows 0..3; stores gated srow0==0) ----
    {
        v8h ef[16];
#pragma unroll
        for (int t = 0; t < 16; t++) ef[t] = *(const v8h*)&El[ar][t * 32 + ag];
        float* op = out + BATCH * NN + ((size_t)(b * NN + i0)) * OBJ_D;
        for (int t5 = w; t5 < 20; t5 += 8) {
            int d0 = t5 * 16;
            if (t5 != w) {
                const __half2* bp = Eb + (size_t)(d0 + ar) * 256 + (ag >> 1);
#pragma unroll
                for (int t = 0; t < 16; t++) eT[t] = *(const v8h*)(bp + t * 16);
            }
            f32x4 cA = {0.0f, 0.0f, 0.0f, 0.0f}, cB = {0.0f, 0.0f, 0.0f, 0.0f};
#pragma unroll
            for (int t = 0; t < 8; t++) {
                cA = __builtin_amdgcn_mfma_f32_16x16x32_f16(ef[2 * t], eT[2 * t], cA, 0, 0, 0);
                cB = __builtin_amdgcn_mfma_f32_16x16x32_f16(ef[2 * t + 1], eT[2 * t + 1], cB, 0, 0, 0);
            }
            f32x4 cc = cA + cB;
            if (srow0 == 0) {
#pragma unroll
                for (int r = 0; r < 4; r++)
                    op[(size_t)r * OBJ_D + d0 + ar] = cc[r] / sumL[r];
            }
        }
    }
}

extern "C" void kernel_launch(void* const* d_in, const int* in_sizes, int n_in,
                              void* d_out, int out_size, void* d_ws, size_t ws_size,
                              hipStream_t stream) {
    const float* emb   = (const float*)d_in[0];
    const float* geom  = (const float*)d_in[1];
    const float* utter = (const float*)d_in[2];
    const float* W1    = (const float*)d_in[3];
    const float* b1    = (const float*)d_in[4];
    const float* W2    = (const float*)d_in[5];
    const float* b2    = (const float*)d_in[6];
    float* out = (float*)d_out;

    float* ws = (float*)d_ws;
    float* hl      = ws;                                    // 512
    float* hi_p    = ws + 512;                              // BATCH*NN*HID
    float* DjP     = hi_p + (size_t)BN * HID;               // 4*BATCH*NN
    _Float16* Bj_h = (_Float16*)(DjP + 4 * BN);             // BATCH*NN*HID f16
    __half2* embT2 = (__half2*)(Bj_h + (size_t)BN * HID);   // BATCH*OBJ_D*256 half2

    hipLaunchKernelGGL(k_pre, dim3(256 + BATCH), dim3(256), 0, stream,
                       emb, geom, utter, W1, b1, W2, embT2, hi_p, Bj_h, hl, DjP);
    hipLaunchKernelGGL(k_main, dim3(BATCH * NN / 4), dim3(512), 0, stream,
                       hi_p, Bj_h, embT2, hl, W2, b2, DjP, out);
}

// Round 9
// 100.331 us; speedup vs baseline: 1.0423x; 1.0423x over previous
//
#include <hip/hip_runtime.h>
#include <hip/hip_fp16.h>
#include <math.h>

#define OBJ_D 320
#define LANG_D 256
#define GEO_D 6
#define HID 256
#define NN 512
#define BATCH 2
#define BN (BATCH * NN)

// gelu(a) ~= 0.5a + GK0*a^2 + GK1*a^4,  GK1 = -GK0/6.
// Factorized: score = Ci + Dj + 2*GK0*sum_h (W2*x_i)*v_j (quartic cross ~1e-8, dropped)
#define GK0 0.3989422804014327f
#define GK1 (-0.066490380066905448f)
#define SCA (512.0f * GK0)
#define INV_SCA (1.0f / 256.0f)

typedef _Float16 v8h __attribute__((ext_vector_type(8)));
typedef float f32x4 __attribute__((ext_vector_type(4)));

__device__ __forceinline__ float wave_allreduce_sum(float v) {
#pragma unroll
    for (int o = 32; o > 0; o >>= 1) v += __shfl_xor(v, o, 64);
    return v;
}

// k_pre v9 = round-4 structure (best measured) with two latency-only edits:
//  (1) W prefetch depth 16 -> 32 dims (10 chunks): 512cy of FMA issue per
//      chunk now covers the ~300-500cy L2 latency of the next chunk's 64
//      loads (R5 counters: VALUBusy 11.7% = chunk-boundary stalls at 1
//      wave/SIMD). Accumulation order over d unchanged -> bit-identical.
//  (2) gw/W2 epilogue loads hoisted before the matmul (fly underneath it).
//  __launch_bounds__(256,1): occupancy is grid-limited at 1 block/CU; make
//  the full VGPR budget explicit (~170 used).
// blocks 256..257 = lang norm + hl matvec (b1 folded).
__global__ __launch_bounds__(256, 1) void k_pre(const float* __restrict__ emb,
                                                const float* __restrict__ geom,
                                                const float* __restrict__ utter,
                                                const float* __restrict__ W1,
                                                const float* __restrict__ b1,
                                                const float* __restrict__ W2,
                                                __half2* __restrict__ embT2,
                                                float* __restrict__ hi_p,
                                                _Float16* __restrict__ Bj_h,
                                                float* __restrict__ hl,
                                                float* __restrict__ DjP) {
    int tid = threadIdx.x;
    int wid = tid >> 6, lane = tid & 63;

    __shared__ alignas(16) float esT[OBJ_D * 20];   // [d][16 rows + pad4]
    __shared__ float gs[16][GEO_D];
    __shared__ float lang_s[LANG_D];
    __shared__ float red[8];

    if (blockIdx.x >= 256) {
        int lb = blockIdx.x - 256;
        float v = utter[lb * LANG_D + tid];
        float ss = wave_allreduce_sum(v * v);
        if (lane == 0) red[wid] = ss;
        __syncthreads();
        if (tid == 0) red[0] = 1.0f / fmaxf(sqrtf(red[0] + red[1] + red[2] + red[3]), 1e-12f);
        __syncthreads();
        lang_s[tid] = v * red[0];
        __syncthreads();
        const float* Wl = W1 + (size_t)(2 * OBJ_D + GEO_D) * HID + tid;
        float acc = b1[tid];
#pragma unroll 8
        for (int l2 = 0; l2 < LANG_D; l2++) acc = fmaf(lang_s[l2], Wl[(size_t)l2 * HID], acc);
        hl[lb * HID + tid] = acc;
        return;
    }

    int q = blockIdx.x & 3;
    int g = blockIdx.x >> 2;
    int b = g & 1;
    int n0 = (g >> 1) * 16;
    int h = q * 64 + lane;     // this thread's H column
    int rg = wid;              // wave owns rows 4*rg .. 4*rg+3

    // stage emb 16 rows x 320 -> esT[d][r] (transposed, +4 pad)
    const float* esrc = emb + (size_t)(b * NN + n0) * OBJ_D;
#pragma unroll
    for (int it = 0; it < 20; it++) {
        int idx = it * 256 + tid;              // 0..5119
        int r = idx / OBJ_D, d = idx - r * OBJ_D;
        esT[d * 20 + r] = esrc[idx];
    }
    if (tid < 16 * GEO_D) gs[tid / GEO_D][tid % GEO_D] = geom[(size_t)(b * NN + n0) * GEO_D + tid];

    // W prefetch (first 32 dims) issues while esT settles; drained at the barrier
    const float* WiC = W1 + h;
    const float* WjC = W1 + (size_t)OBJ_D * HID + h;
    float wi[32], wj[32], win[32], wjn[32];
#pragma unroll
    for (int k = 0; k < 32; k++) {
        wi[k] = WiC[(size_t)k * HID];
        wj[k] = WjC[(size_t)k * HID];
    }
    // epilogue operands issued early (fly under the matmul)
    float gw[GEO_D];
#pragma unroll
    for (int gg = 0; gg < GEO_D; gg++) gw[gg] = W1[(size_t)(2 * OBJ_D + gg) * HID + h];
    float w2v = W2[h];
    __syncthreads();

    // per-wave norms for its 4 rows (wave-local; no broadcast barrier)
    float rnv[4];
    {
        float sq0 = 0.0f, sq1 = 0.0f, sq2 = 0.0f, sq3 = 0.0f;
#pragma unroll
        for (int it = 0; it < 5; it++) {
            float4 e4 = *(const float4*)&esT[(lane + 64 * it) * 20 + 4 * rg];
            sq0 = fmaf(e4.x, e4.x, sq0); sq1 = fmaf(e4.y, e4.y, sq1);
            sq2 = fmaf(e4.z, e4.z, sq2); sq3 = fmaf(e4.w, e4.w, sq3);
        }
        rnv[0] = 1.0f / fmaxf(sqrtf(wave_allreduce_sum(sq0)), 1e-12f);
        rnv[1] = 1.0f / fmaxf(sqrtf(wave_allreduce_sum(sq1)), 1e-12f);
        rnv[2] = 1.0f / fmaxf(sqrtf(wave_allreduce_sum(sq2)), 1e-12f);
        rnv[3] = 1.0f / fmaxf(sqrtf(wave_allreduce_sum(sq3)), 1e-12f);
    }

    // embT2[b][d][jpair] from q==0 blocks only; wave w writes its own 2 pairs
    if (q == 0) {
#pragma unroll
        for (int it = 0; it < 10; it++) {
            int idx = it * 64 + lane;          // 0..639
            int d = idx >> 1, pp = idx & 1;
            int rp = 2 * rg + pp;
            float ra = pp ? rnv[2] : rnv[0];
            float rc = pp ? rnv[3] : rnv[1];
            float a = esT[d * 20 + 2 * rp] * ra;
            float c = esT[d * 20 + 2 * rp + 1] * rc;
            embT2[((size_t)(b * OBJ_D + d)) * 256 + (n0 >> 1) + rp] = __floats2half2_rn(a, c);
        }
    }

    // dual matmul on UNNORMALIZED esT (rows 4rg..4rg+3, this thread's h col);
    // 32-dim chunks, 2-deep double-buffer; d-ascending accumulation (order
    // identical to round 4 -> bit-identical results).
    float ai[4] = {0, 0, 0, 0}, aj[4] = {0, 0, 0, 0};
    for (int d0 = 0; d0 < OBJ_D; d0 += 32) {
        if (d0 + 32 < OBJ_D) {
#pragma unroll
            for (int k = 0; k < 32; k++) {
                win[k] = WiC[(size_t)(d0 + 32 + k) * HID];
                wjn[k] = WjC[(size_t)(d0 + 32 + k) * HID];
            }
        }
#pragma unroll
        for (int k = 0; k < 32; k++) {
            float4 e4 = *(const float4*)&esT[(d0 + k) * 20 + 4 * rg];   // wave-uniform broadcast
            ai[0] = fmaf(e4.x, wi[k], ai[0]); aj[0] = fmaf(e4.x, wj[k], aj[0]);
            ai[1] = fmaf(e4.y, wi[k], ai[1]); aj[1] = fmaf(e4.y, wj[k], aj[1]);
            ai[2] = fmaf(e4.z, wi[k], ai[2]); aj[2] = fmaf(e4.z, wj[k], aj[2]);
            ai[3] = fmaf(e4.w, wi[k], ai[3]); aj[3] = fmaf(e4.w, wj[k], aj[3]);
        }
#pragma unroll
        for (int k = 0; k < 32; k++) { wi[k] = win[k]; wj[k] = wjn[k]; }
    }

#pragma unroll
    for (int r = 0; r < 4; r++) {
        int row = 4 * rg + r;
        float gp = 0.0f;
#pragma unroll
        for (int gg = 0; gg < GEO_D; gg++) gp = fmaf(gs[row][gg], gw[gg], gp);
        float yi = ai[r] * rnv[r] - gp;
        float vjv = aj[r] * rnv[r] + gp;
        hi_p[(size_t)(b * NN + n0 + row) * HID + h] = yi;
        Bj_h[((size_t)(b * NN + n0 + row)) * HID + h] = (_Float16)vjv;
        float v2 = vjv * vjv;
        float sj = fmaf(v2, fmaf(GK1, v2, GK0), 0.5f * vjv);
        float ds = wave_allreduce_sum(w2v * sj);   // partial over this block's 64 h
        if (lane == 0) DjP[q * BN + b * NN + n0 + row] = ds;
    }
}

__device__ __forceinline__ void load_tile8(v8h* dst, const _Float16* bp) {
#pragma unroll
    for (int t = 0; t < 8; t++) dst[t] = *(const v8h*)(bp + t * 32);
}

__device__ __forceinline__ void score_tile(const v8h* afr, const v8h* bt,
                                           float (*S)[516], int srow0, int col, float dj) {
    f32x4 cA = {0.0f, 0.0f, 0.0f, 0.0f}, cB = {0.0f, 0.0f, 0.0f, 0.0f};
#pragma unroll
    for (int t = 0; t < 4; t++) {
        cA = __builtin_amdgcn_mfma_f32_16x16x32_f16(afr[2 * t], bt[2 * t], cA, 0, 0, 0);
        cB = __builtin_amdgcn_mfma_f32_16x16x32_f16(afr[2 * t + 1], bt[2 * t + 1], cB, 0, 0, 0);
    }
    f32x4 cc = cA + cB;
#pragma unroll
    for (int r = 0; r < 4; r++) S[srow0 + r][col] = cc[r] * INV_SCA + dj;
}

// k_main v9 = verified round-4 source verbatim: phase 0 (hi+hl -> As f16, Ci
// exact) + 2-deep pipelined score GEMM + softmax + context GEMM, with
// cross-barrier prefetches throughout.
__global__ __launch_bounds__(512, 2) void k_main(const float* __restrict__ hi_p,
                                                 const _Float16* __restrict__ Bj_h,
                                                 const __half2* __restrict__ embT2,
                                                 const float* __restrict__ hl,
                                                 const float* __restrict__ W2,
                                                 const float* __restrict__ b2p,
                                                 const float* __restrict__ DjP,
                                                 float* __restrict__ out) {
    int b = blockIdx.x & 1;
    int i0 = (blockIdx.x >> 1) * 16;
    int tid = threadIdx.x;
    int lane = tid & 63, w = tid >> 6;
    int ar = lane & 15, ag = (lane >> 4) * 8;
    int srow0 = (lane >> 4) * 4;

    __shared__ alignas(16) _Float16 As[16][264];
    __shared__ float S[16][516];
    __shared__ alignas(16) _Float16 El[16][520];
    __shared__ float CiTs[16], sumL[16], dotL[16];

    const _Float16* Bb = Bj_h + (size_t)b * NN * HID;
    const float* Djb = DjP + b * NN;
    int jt0 = w * 4;

    // pre-barrier prefetch: q=0 B-tile + all Dj partials (independent of As)
    v8h bA[8], bB[8];
    float dj[4];
    load_tile8(bA, Bb + (size_t)(jt0 * 16 + ar) * HID + ag);
#pragma unroll
    for (int qq = 0; qq < 4; qq++) {
        int jj = (jt0 + qq) * 16 + ar;
        dj[qq] = (Djb[jj] + Djb[jj + BN]) + (Djb[jj + 2 * BN] + Djb[jj + 3 * BN]);
    }

    // ---- phase 0: As = SCA*W2*(hi+hl) f16; Ci exact fp32 ----
    {
        int row = tid >> 5;
        int hq = (tid & 31) * 8;
        const float* hp = hi_p + ((size_t)(b * NN + i0 + row)) * HID + hq;
        const float* hlp = hl + b * HID + hq;
        const float* w2p = W2 + hq;
        float ci = 0.0f;
        v8h av;
#pragma unroll
        for (int k = 0; k < 8; k++) {
            float x = hp[k] + hlp[k];
            float w2k = w2p[k];
            av[k] = (_Float16)(x * w2k * SCA);
            float x2 = x * x;
            ci = fmaf(w2k, fmaf(x2, fmaf(GK1, x2, GK0), 0.5f * x), ci);
        }
        *(v8h*)&As[row][hq] = av;
#pragma unroll
        for (int o = 16; o > 0; o >>= 1) ci += __shfl_xor(ci, o, 64);
        if ((tid & 31) == 0) CiTs[row] = ci;
    }
    __syncthreads();

    // ---- phase 1: score cross GEMM, 2-deep pipeline ----
    {
        v8h afr[8];
#pragma unroll
        for (int t = 0; t < 8; t++) afr[t] = *(const v8h*)&As[ar][t * 32 + ag];
        load_tile8(bB, Bb + (size_t)((jt0 + 1) * 16 + ar) * HID + ag);
        score_tile(afr, bA, S, srow0, jt0 * 16 + ar, dj[0]);
        load_tile8(bA, Bb + (size_t)((jt0 + 2) * 16 + ar) * HID + ag);
        score_tile(afr, bB, S, srow0, (jt0 + 1) * 16 + ar, dj[1]);
        load_tile8(bB, Bb + (size_t)((jt0 + 3) * 16 + ar) * HID + ag);
        score_tile(afr, bA, S, srow0, (jt0 + 2) * 16 + ar, dj[2]);
        score_tile(afr, bB, S, srow0, (jt0 + 3) * 16 + ar, dj[3]);
    }
    __syncthreads();

    // phase-3 first-tile prefetch: flies under the softmax VALU work
    const __half2* Eb = embT2 + (size_t)b * OBJ_D * 256;
    v8h eT[16];
    {
        const __half2* bp = Eb + (size_t)(w * 16 + ar) * 256 + (ag >> 1);
#pragma unroll
        for (int t = 0; t < 16; t++) eT[t] = *(const v8h*)(bp + t * 16);
    }

    // ---- phase 2: softmax (row = tid>>5, 32 threads/row) ----
    {
        int row = tid >> 5, gg = tid & 31;
        float sv[16];
#pragma unroll
        for (int jj = 0; jj < 16; jj++) sv[jj] = S[row][gg + 32 * jj];
        float m = sv[0];
#pragma unroll
        for (int jj = 1; jj < 16; jj++) m = fmaxf(m, sv[jj]);
#pragma unroll
        for (int o = 16; o > 0; o >>= 1) m = fmaxf(m, __shfl_xor(m, o, 64));
        float se = 0.0f, sd = 0.0f;
#pragma unroll
        for (int jj = 0; jj < 16; jj++) {
            float e = __expf(sv[jj] - m);
            se += e;
            sd = fmaf(e, sv[jj], sd);
            El[row][gg + 32 * jj] = (_Float16)e;
        }
#pragma unroll
        for (int o = 16; o > 0; o >>= 1) { se += __shfl_xor(se, o, 64); sd += __shfl_xor(sd, o, 64); }
        if (gg == 0) { sumL[row] = se; dotL[row] = sd; }
    }
    __syncthreads();

    if (tid < 16)
        out[b * NN + i0 + tid] = CiTs[tid] + b2p[0] + dotL[tid] / sumL[tid];

    // ---- phase 3: context GEMM (per-thread redundant 1/sum, no extra barrier) ----
    {
        float iv[4];
#pragma unroll
        for (int r = 0; r < 4; r++) iv[r] = 1.0f / sumL[srow0 + r];
        v8h ef[16];
#pragma unroll
        for (int t = 0; t < 16; t++) ef[t] = *(const v8h*)&El[ar][t * 32 + ag];
        float* op = out + BATCH * NN + ((size_t)(b * NN + i0)) * OBJ_D;
        for (int t5 = w; t5 < 20; t5 += 8) {
            int d0 = t5 * 16;
            if (t5 != w) {
                const __half2* bp = Eb + (size_t)(d0 + ar) * 256 + (ag >> 1);
#pragma unroll
                for (int t = 0; t < 16; t++) eT[t] = *(const v8h*)(bp + t * 16);
            }
            f32x4 cA = {0.0f, 0.0f, 0.0f, 0.0f}, cB = {0.0f, 0.0f, 0.0f, 0.0f};
#pragma unroll
            for (int t = 0; t < 8; t++) {
                cA = __builtin_amdgcn_mfma_f32_16x16x32_f16(ef[2 * t], eT[2 * t], cA, 0, 0, 0);
                cB = __builtin_amdgcn_mfma_f32_16x16x32_f16(ef[2 * t + 1], eT[2 * t + 1], cB, 0, 0, 0);
            }
            f32x4 cc = cA + cB;
#pragma unroll
            for (int r = 0; r < 4; r++)
                op[(size_t)(srow0 + r) * OBJ_D + d0 + ar] = cc[r] * iv[r];
        }
    }
}

extern "C" void kernel_launch(void* const* d_in, const int* in_sizes, int n_in,
                              void* d_out, int out_size, void* d_ws, size_t ws_size,
                              hipStream_t stream) {
    const float* emb   = (const float*)d_in[0];
    const float* geom  = (const float*)d_in[1];
    const float* utter = (const float*)d_in[2];
    const float* W1    = (const float*)d_in[3];
    const float* b1    = (const float*)d_in[4];
    const float* W2    = (const float*)d_in[5];
    const float* b2    = (const float*)d_in[6];
    float* out = (float*)d_out;

    float* ws = (float*)d_ws;
    float* hl      = ws;                                    // 512
    float* hi_p    = ws + 512;                              // BATCH*NN*HID
    float* DjP     = hi_p + (size_t)BN * HID;               // 4*BATCH*NN
    _Float16* Bj_h = (_Float16*)(DjP + 4 * BN);             // BATCH*NN*HID f16
    __half2* embT2 = (__half2*)(Bj_h + (size_t)BN * HID);   // BATCH*OBJ_D*256 half2

    hipLaunchKernelGGL(k_pre, dim3(256 + BATCH), dim3(256), 0, stream,
                       emb, geom, utter, W1, b1, W2, embT2, hi_p, Bj_h, hl, DjP);
    hipLaunchKernelGGL(k_main, dim3(BATCH * NN / 16), dim3(512), 0, stream,
                       hi_p, Bj_h, embT2, hl, W2, b2, DjP, out);
}